// Round 10
// baseline (147.605 us; speedup 1.0000x reference)
//
#include <hip/hip_runtime.h>

#define N_CH 7
#define N_CELLS 3000
#define EPB 38458u      // floats per batch (== 2 mod 4)
#define PAIR 76916u     // floats per 2 batches (== 0 mod 4)
#define XROW 119
#define XPAIR 238
#define XTOT (2048 * XROW)           // 243712 floats of x total
#define SENT (-8)

typedef float f32x4 __attribute__((ext_vector_type(4)));

// ws layout: [table: 76916 shorts = 153832 B][round to 153856][64 B front pad]
//            [x copy: 243712 floats][16 B back pad]
#define XCOPY_BYTE_OFF (153856 + 64)

// Merged setup: direct table build (cell_lin == arange) + padded x copy.
__global__ void prep2_k(const float* __restrict__ x, const int* __restrict__ rid,
                        short* __restrict__ t, float* __restrict__ xc) {
    unsigned i = blockIdx.x * blockDim.x + threadIdx.x;
    if (i < XTOT) xc[i] = x[i];
    if (i < PAIR) {
        unsigned lb = (i >= EPB) ? 1u : 0u;
        unsigned j = i - lb * EPB;
        unsigned c = j / 7u;                 // compiler magic-mul
        unsigned ch = j - c * 7u;
        short v = SENT;
        if (c < N_CELLS) v = (short)(lb * XROW + rid[c] * N_CH + ch);
        t[i] = v;
    }
}

__device__ __forceinline__ f32x4 gsel(const float* __restrict__ xb, short4 s) {
    // Two dwordx4 gathers cover both possible source runs (7-float runs).
    // Pads guarantee in-bounds even for sentinel (-8) lanes.
    f32x4 A = *reinterpret_cast<const f32x4*>(xb + (int)s.x);
    f32x4 B = *reinterpret_cast<const f32x4*>(xb + (int)s.w - 3);
    f32x4 v;
    v.x = (s.x >= 0) ? A.x : 0.f;
    v.y = (s.y >= 0) ? ((s.y == s.x + 1) ? A.y : B.y) : 0.f;
    v.z = (s.z >= 0) ? ((s.z == s.x + 2) ? A.z : B.z) : 0.f;
    v.w = (s.w >= 0) ? B.w : 0.f;
    return v;
}

// R6's global linear sweep with x2 ADJACENT unroll: each thread owns windows
// 2i and 2i+1 (32 B contiguous); wave front stays one contiguous 2 KB run.
__global__ __launch_bounds__(256) void fill9_k(const float* __restrict__ xc,
                                               const short* __restrict__ t,
                                               float* __restrict__ out,
                                               unsigned total8) {
    unsigned stride = gridDim.x * blockDim.x;
    for (unsigned i = blockIdx.x * blockDim.x + threadIdx.x; i < total8; i += stride) {
        unsigned e0 = i * 8u;
        unsigned e1 = e0 + 4u;
        unsigned p0 = e0 / PAIR;             // magic-mul
        unsigned off0 = e0 - p0 * PAIR;
        unsigned p1 = e1 / PAIR;
        unsigned off1 = e1 - p1 * PAIR;
        short4 s0 = *reinterpret_cast<const short4*>(t + off0);   // 8B, L2-resident
        short4 s1 = *reinterpret_cast<const short4*>(t + off1);
        f32x4 v0 = gsel(xc + p0 * XPAIR, s0);
        f32x4 v1 = gsel(xc + p1 * XPAIR, s1);
        __builtin_nontemporal_store(v0, reinterpret_cast<f32x4*>(out + e0));
        __builtin_nontemporal_store(v1, reinterpret_cast<f32x4*>(out + e1));
    }
}

extern "C" void kernel_launch(void* const* d_in, const int* in_sizes, int n_in,
                              void* d_out, int out_size, void* d_ws, size_t ws_size,
                              hipStream_t stream) {
    const float* x        = (const float*)d_in[0];
    const int* region_ids = (const int*)d_in[2];
    float* out = (float*)d_out;
    short* table = (short*)d_ws;
    float* xcopy = (float*)((char*)d_ws + XCOPY_BYTE_OFF);

    prep2_k<<<(XTOT + 255) / 256, 256, 0, stream>>>(x, region_ids, table, xcopy);

    unsigned total8 = (unsigned)out_size / 8u;   // 9,845,248 windows of 8 floats
    fill9_k<<<2048, 256, 0, stream>>>(xcopy, table, out, total8);
}

// Round 11
// 65.217 us; speedup vs baseline: 2.2633x; 2.2633x over previous
//
#include <hip/hip_runtime.h>

#define N_CH 7
#define N_MAP 5494
#define EPB 38458u      // floats per batch (== 2 mod 4)
#define PAIR 76916u     // floats per 2 batches (== 0 mod 4)
#define XROW 119
#define XPAIR 238
#define XTOT (2048 * XROW)           // 243712 floats of x total
#define SENT (-8)

typedef float f32x4 __attribute__((ext_vector_type(4)));

// ws layout: [table: 76916 shorts = 153832 B][round to 153856][64 B front pad]
//            [x copy: 243712 floats][16 B back pad]
#define XCOPY_BYTE_OFF (153856 + 64)

__global__ void prep_k(const float* __restrict__ x, short* __restrict__ t,
                       float* __restrict__ xc) {
    int i = blockIdx.x * blockDim.x + threadIdx.x;
    if (i < (int)PAIR) t[i] = SENT;
    if (i < XTOT) xc[i] = x[i];
}

__global__ void scatter_table_k(const int* __restrict__ cl,
                                const int* __restrict__ rid,
                                int n, short* __restrict__ t) {
    int i = blockIdx.x * blockDim.x + threadIdx.x;
    if (i >= n) return;
    int c = cl[i], r = rid[i];
    if (c < 0 || c >= N_MAP) return;
#pragma unroll
    for (int lb = 0; lb < 2; ++lb) {
        int dst = lb * (int)EPB + c * N_CH;
        short src = (short)(lb * XROW + r * N_CH);
#pragma unroll
        for (int ch = 0; ch < N_CH; ++ch) t[dst + ch] = (short)(src + ch);
    }
}

// R6 body, with PLAIN stores (NT flag removed — single-variable A/B vs R6).
__global__ __launch_bounds__(256) void fill10_k(const float* __restrict__ xc,
                                                const short* __restrict__ t,
                                                float* __restrict__ out,
                                                unsigned total4) {
    unsigned stride = gridDim.x * blockDim.x;
    for (unsigned i = blockIdx.x * blockDim.x + threadIdx.x; i < total4; i += stride) {
        unsigned e0 = i * 4u;
        unsigned p = e0 / PAIR;              // magic-mul
        unsigned off = e0 - p * PAIR;        // multiple of 4 -> 8B-aligned table read
        short4 s = *reinterpret_cast<const short4*>(t + off);
        f32x4 v = {0.f, 0.f, 0.f, 0.f};
        if (__any((s.x >= 0) || (s.w >= 0))) {       // any-valid <=> x or w valid (7-runs)
            const float* xb = xc + p * XPAIR;
            f32x4 A = *reinterpret_cast<const f32x4*>(xb + (int)s.x);
            f32x4 B = *reinterpret_cast<const f32x4*>(xb + (int)s.w - 3);
            v.x = (s.x >= 0) ? A.x : 0.f;
            v.y = (s.y >= 0) ? ((s.y == s.x + 1) ? A.y : B.y) : 0.f;
            v.z = (s.z >= 0) ? ((s.z == s.x + 2) ? A.z : B.z) : 0.f;
            v.w = (s.w >= 0) ? B.w : 0.f;
        }
        *reinterpret_cast<f32x4*>(out + e0) = v;     // plain cached store
    }
}

extern "C" void kernel_launch(void* const* d_in, const int* in_sizes, int n_in,
                              void* d_out, int out_size, void* d_ws, size_t ws_size,
                              hipStream_t stream) {
    const float* x        = (const float*)d_in[0];
    const int* cell_lin   = (const int*)d_in[1];
    const int* region_ids = (const int*)d_in[2];
    float* out = (float*)d_out;
    short* table = (short*)d_ws;
    float* xcopy = (float*)((char*)d_ws + XCOPY_BYTE_OFF);
    int n_cells = in_sizes[1];

    prep_k<<<(XTOT + 255) / 256, 256, 0, stream>>>(x, table, xcopy);
    scatter_table_k<<<(n_cells + 255) / 256, 256, 0, stream>>>(cell_lin, region_ids, n_cells, table);

    unsigned total4 = (unsigned)out_size / 4u;
    fill10_k<<<2048, 256, 0, stream>>>(xcopy, table, out, total4);
}

// Round 12
// 61.528 us; speedup vs baseline: 2.3990x; 1.0600x over previous
//
#include <hip/hip_runtime.h>

#define N_CH 7
#define N_MAP 5494
#define EPB 38458u      // floats per batch (== 2 mod 4)
#define PAIR 76916u     // floats per 2 batches (== 0 mod 4)
#define XROW 119
#define XPAIR 238
#define XTOT (2048 * XROW)           // 243712 floats of x total
#define SENT (-8)

typedef float f32x4 __attribute__((ext_vector_type(4)));

// ws layout: [table: 76916 shorts = 153832 B][round to 153856][64 B front pad]
//            [x copy: 243712 floats][16 B back pad]
#define XCOPY_BYTE_OFF (153856 + 64)

__global__ void prep_k(const float* __restrict__ x, short* __restrict__ t,
                       float* __restrict__ xc) {
    int i = blockIdx.x * blockDim.x + threadIdx.x;
    if (i < (int)PAIR) t[i] = SENT;
    if (i < XTOT) xc[i] = x[i];
}

__global__ void scatter_table_k(const int* __restrict__ cl,
                                const int* __restrict__ rid,
                                int n, short* __restrict__ t) {
    int i = blockIdx.x * blockDim.x + threadIdx.x;
    if (i >= n) return;
    int c = cl[i], r = rid[i];
    if (c < 0 || c >= N_MAP) return;
#pragma unroll
    for (int lb = 0; lb < 2; ++lb) {
        int dst = lb * (int)EPB + c * N_CH;
        short src = (short)(lb * XROW + r * N_CH);
#pragma unroll
        for (int ch = 0; ch < N_CH; ++ch) t[dst + ch] = (short)(src + ch);
    }
}

__device__ __forceinline__ f32x4 gsel(const float* __restrict__ xb, short4 s) {
    // Two dwordx4 gathers cover both possible source runs (7-float runs).
    // Pads guarantee in-bounds even for sentinel (-8) lanes.
    f32x4 A = *reinterpret_cast<const f32x4*>(xb + (int)s.x);
    f32x4 B = *reinterpret_cast<const f32x4*>(xb + (int)s.w - 3);
    f32x4 v;
    v.x = (s.x >= 0) ? A.x : 0.f;
    v.y = (s.y >= 0) ? ((s.y == s.x + 1) ? A.y : B.y) : 0.f;
    v.z = (s.z >= 0) ? ((s.z == s.x + 2) ? A.z : B.z) : 0.f;
    v.w = (s.w >= 0) ? B.w : 0.f;
    return v;
}

// R6 geometry with x2 ILP: thread handles windows i and i+64. Each store
// instruction's 64 lanes cover one contiguous 1 KB run (16 B/lane); the two
// stores are adjacent 1 KB runs -> wave front 2 KB contiguous, as in R6.
__global__ __launch_bounds__(256) void fill11_k(const float* __restrict__ xc,
                                                const short* __restrict__ t,
                                                float* __restrict__ out,
                                                unsigned total4) {
    unsigned lane = threadIdx.x & 63u;
    unsigned wv   = threadIdx.x >> 6;            // wave id in block (0..3)
    unsigned base = blockIdx.x * 512u + wv * 128u + lane;
    unsigned stride = gridDim.x * 512u;
    for (unsigned i0 = base; i0 < total4; i0 += stride) {
        unsigned i1 = i0 + 64u;                  // wave-uniform validity (total4 % 64 == 0)
        bool have1 = i1 < total4;
        unsigned e0 = i0 * 4u;
        unsigned e1 = e0 + 256u;
        unsigned p0 = e0 / PAIR;                 // magic-mul
        unsigned off0 = e0 - p0 * PAIR;
        unsigned p1 = e1 / PAIR;
        unsigned off1 = e1 - p1 * PAIR;          // always < PAIR: table read safe
        short4 s0 = *reinterpret_cast<const short4*>(t + off0);
        short4 s1 = *reinterpret_cast<const short4*>(t + off1);
        f32x4 v0 = {0.f, 0.f, 0.f, 0.f};
        f32x4 v1 = {0.f, 0.f, 0.f, 0.f};
        if (__any(s0.x >= 0 || s0.w >= 0))
            v0 = gsel(xc + p0 * XPAIR, s0);
        if (have1 && __any(s1.x >= 0 || s1.w >= 0))
            v1 = gsel(xc + p1 * XPAIR, s1);
        *reinterpret_cast<f32x4*>(out + e0) = v0;
        if (have1) *reinterpret_cast<f32x4*>(out + e1) = v1;
    }
}

extern "C" void kernel_launch(void* const* d_in, const int* in_sizes, int n_in,
                              void* d_out, int out_size, void* d_ws, size_t ws_size,
                              hipStream_t stream) {
    const float* x        = (const float*)d_in[0];
    const int* cell_lin   = (const int*)d_in[1];
    const int* region_ids = (const int*)d_in[2];
    float* out = (float*)d_out;
    short* table = (short*)d_ws;
    float* xcopy = (float*)((char*)d_ws + XCOPY_BYTE_OFF);
    int n_cells = in_sizes[1];

    prep_k<<<(XTOT + 255) / 256, 256, 0, stream>>>(x, table, xcopy);
    scatter_table_k<<<(n_cells + 255) / 256, 256, 0, stream>>>(cell_lin, region_ids, n_cells, table);

    unsigned total4 = (unsigned)out_size / 4u;
    fill11_k<<<2048, 256, 0, stream>>>(xcopy, table, out, total4);
}